// Round 4
// baseline (2274.719 us; speedup 1.0000x reference)
//
#include <hip/hip_runtime.h>
#include <cstdint>
#include <cstddef>

#define BB 8
#define NN 8192
#define CC 64
#define MM 2048
#define KK 32

typedef float vfloat2 __attribute__((ext_vector_type(2)));

__device__ __forceinline__ float sqdist_exact(float x, float y, float z,
                                              float cx, float cy, float cz) {
    // Replicate numpy/JAX f32: (x-c)**2 summed ((dx2+dy2)+dz2), no FMA contraction.
    float dx = __fsub_rn(x, cx);
    float dy = __fsub_rn(y, cy);
    float dz = __fsub_rn(z, cz);
    return __fadd_rn(__fadd_rn(__fmul_rn(dx, dx), __fmul_rn(dy, dy)),
                     __fmul_rn(dz, dz));
}

// ---- DPP wave64 reduce ladder pieces (row_shr:N = 0x110|N, bcast15/31 = 0x142/0x143) ----
// max over nonneg f32 reinterpreted as u32 (identical ordering); bound_ctrl=true -> 0 never wins max.
template <int CTRL>
__device__ __forceinline__ unsigned dpp_max_u32(unsigned v) {
    unsigned s = (unsigned)__builtin_amdgcn_update_dpp(0, (int)v, CTRL, 0xF, 0xF, true);
    return v > s ? v : s;
}
// min over u32 indices; bound_ctrl=false with old=INT_MAX -> invalid lanes never win min.
template <int CTRL>
__device__ __forceinline__ unsigned dpp_min_u32(unsigned v) {
    unsigned s = (unsigned)__builtin_amdgcn_update_dpp(0x7FFFFFFF, (int)v, CTRL, 0xF, 0xF, false);
    return v < s ? v : s;
}

// Octile boundaries of N(0,1): equal-mass 8-way split per dimension.
__device__ __forceinline__ int octile(float v) {
    return (v > -1.1503494f) + (v > -0.6744898f) + (v > -0.3186394f) + (v > 0.0f) +
           (v > 0.3186394f) + (v > 0.6744898f) + (v > 1.1503494f);
}

// 9-bit Morton interleave of three 3-bit coords: consecutive bin ids are
// spatially compact (each wave's 64 bins form a 4x4x4 sub-cube).
__device__ __forceinline__ int morton9(int bx, int by, int bz) {
    int m = (bz & 1) | ((bz & 2) << 2) | ((bz & 4) << 4);
    m |= ((by & 1) << 1) | ((by & 2) << 3) | ((by & 4) << 5);
    m |= ((bx & 1) << 2) | ((bx & 2) << 4) | ((bx & 4) << 6);
    return m;
}

// ---------------- FPS: one block per batch, 512 threads ----------------
// Exact spatial pruning (bit-exact skip via per-chunk bbox lower bound).
// v4: packed vfloat2 update body (v_pk_* halves issue), wave-uniform skip of
// BOTH the update and the DPP reduce ladders (a fully-pruned wave's
// (max,argmin) key is unchanged -> carried in a register and re-stored by
// lane 63 only), no global ops inside the loop.
__global__ __launch_bounds__(512) void fps_kernel(const float* __restrict__ x,
                                                  int* __restrict__ fps_idx) {
#pragma clang fp contract(off)
    const int b = blockIdx.x;
    const int tid = threadIdx.x;
    const int lane = tid & 63;
    const int wv = tid >> 6;
    const float* xb = x + (size_t)b * 3 * NN;
    int* fps_store = fps_idx + b * MM;

    __shared__ float sx[NN];   // original-index order (centroid lookup)
    __shared__ float sy[NN];
    __shared__ float sz[NN];
    __shared__ int sidx[NN];   // binned order -> original index
    __shared__ int hist[512];
    __shared__ int scanb[512];
    __shared__ int sfps[MM];   // selected indices, dumped to global at the end
    __shared__ unsigned long long red2[2][8];

    const vfloat2* gx = (const vfloat2*)xb;
    const vfloat2* gy = (const vfloat2*)(xb + NN);
    const vfloat2* gz = (const vfloat2*)(xb + 2 * NN);

    vfloat2 lx[8], ly[8], lz[8];
#pragma unroll
    for (int p = 0; p < 8; ++p) {
        const int e = tid + p * 512;  // float2 slot; covers points 2e, 2e+1
        lx[p] = gx[e];
        ly[p] = gy[e];
        lz[p] = gz[e];
        ((vfloat2*)sx)[e] = lx[p];
        ((vfloat2*)sy)[e] = ly[p];
        ((vfloat2*)sz)[e] = lz[p];
    }
    hist[tid] = 0;
    __syncthreads();

    // ---- histogram over 512 morton-octile bins (from registers) ----
    int mybin[16];
#pragma unroll
    for (int p = 0; p < 8; ++p) {
        int b0 = morton9(octile(lx[p].x), octile(ly[p].x), octile(lz[p].x));
        int b1 = morton9(octile(lx[p].y), octile(ly[p].y), octile(lz[p].y));
        mybin[2 * p] = b0;
        mybin[2 * p + 1] = b1;
        atomicAdd(&hist[b0], 1);
        atomicAdd(&hist[b1], 1);
    }
    __syncthreads();
    // ---- exclusive prefix sum (Hillis-Steele, 512 threads == 512 bins) ----
    int own = hist[tid];
    scanb[tid] = own;
    __syncthreads();
    for (int off = 1; off < 512; off <<= 1) {
        int add = (tid >= off) ? scanb[tid - off] : 0;
        __syncthreads();
        scanb[tid] += add;
        __syncthreads();
    }
    hist[tid] = scanb[tid] - own;  // per-bin scatter cursor
    __syncthreads();
    // ---- scatter original indices into binned order ----
#pragma unroll
    for (int p = 0; p < 8; ++p) {
        const int i0 = 2 * (tid + p * 512);
        int pos0 = atomicAdd(&hist[mybin[2 * p]], 1);
        sidx[pos0] = i0;
        int pos1 = atomicAdd(&hist[mybin[2 * p + 1]], 1);
        sidx[pos1] = i0 + 1;
    }
    __syncthreads();

    // ---- gather this thread's 16-point chunk (packed pairs) + bbox ----
    vfloat2 px[8], py[8], pz[8], dist[8];
    int idxr[16];
#pragma unroll
    for (int p = 0; p < 8; ++p) {
        const int j0 = sidx[tid * 16 + 2 * p];
        const int j1 = sidx[tid * 16 + 2 * p + 1];
        idxr[2 * p] = j0;
        idxr[2 * p + 1] = j1;
        px[p] = (vfloat2){sx[j0], sx[j1]};
        py[p] = (vfloat2){sy[j0], sy[j1]};
        pz[p] = (vfloat2){sz[j0], sz[j1]};
        dist[p] = (vfloat2){INFINITY, INFINITY};
    }
    float blx = fminf(px[0].x, px[0].y), bhx = fmaxf(px[0].x, px[0].y);
    float bly = fminf(py[0].x, py[0].y), bhy = fmaxf(py[0].x, py[0].y);
    float blz = fminf(pz[0].x, pz[0].y), bhz = fmaxf(pz[0].x, pz[0].y);
#pragma unroll
    for (int p = 1; p < 8; ++p) {
        blx = fminf(blx, fminf(px[p].x, px[p].y));
        bhx = fmaxf(bhx, fmaxf(px[p].x, px[p].y));
        bly = fminf(bly, fminf(py[p].x, py[p].y));
        bhy = fmaxf(bhy, fmaxf(py[p].x, py[p].y));
        blz = fminf(blz, fminf(pz[p].x, pz[p].y));
        bhz = fmaxf(bhz, fmaxf(pz[p].x, pz[p].y));
    }

    float cmax = INFINITY;           // exact max of this chunk's current dists
    int cidx = idxr[0];              // smallest original index achieving cmax
    unsigned long long wkey = 0;     // this wave's packed (max, ~argmin); valid on lane 63,
                                     // refreshed whenever the wave is active (t=0: all active)
    int far = 0;
    for (int t = 0; t < MM; ++t) {
        if (tid == 0) sfps[t] = far;  // LDS only: no vmcnt drain at the barrier
        const float cx = sx[far];
        const float cy = sy[far];
        const float cz = sz[far];

        // Lower bound on d^2(c, bbox) via clamp (v_med3). 0.999f margin >>
        // f32 rounding slack (~1.5e-6 rel) between this bound and the exact
        // per-point pipeline, so skipping is guaranteed a value-exact no-op.
        float qx = cx - fminf(fmaxf(cx, blx), bhx);
        float qy = cy - fminf(fmaxf(cy, bly), bhy);
        float qz = cz - fminf(fmaxf(cz, blz), bhz);
        float bound = (qx * qx + qy * qy) + qz * qz;
        const bool act = !(bound * 0.999f >= cmax);
        if (__ballot(act) != 0ull) {  // wave-uniform: skip update AND reduce
            if (act) {
                const vfloat2 cx2 = {cx, cx};
                const vfloat2 cy2 = {cy, cy};
                const vfloat2 cz2 = {cz, cz};
                float mv = -1.0f;
#pragma unroll
                for (int p = 0; p < 8; ++p) {
                    vfloat2 dx = px[p] - cx2;   // v_pk_add_f32
                    vfloat2 dy = py[p] - cy2;
                    vfloat2 dz = pz[p] - cz2;
                    vfloat2 m1 = dx * dx;       // v_pk_mul_f32
                    vfloat2 m2 = dy * dy;
                    vfloat2 m3 = dz * dz;
                    vfloat2 s = (m1 + m2) + m3; // matches reference order
                    vfloat2 nd;
                    nd.x = fminf(dist[p].x, s.x);
                    nd.y = fminf(dist[p].y, s.y);
                    dist[p] = nd;
                    mv = fmaxf(fmaxf(mv, nd.x), nd.y);  // -> v_max3_f32
                }
                // smallest ORIGINAL index among chunk maxima
                int mi = 0x7FFFFFFF;
#pragma unroll
                for (int p = 0; p < 8; ++p) {
                    mi = min(mi, (dist[p].x == mv) ? idxr[2 * p] : 0x7FFFFFFF);
                    mi = min(mi, (dist[p].y == mv) ? idxr[2 * p + 1] : 0x7FFFFFFF);
                }
                cmax = mv;
                cidx = mi;
            }
            // ---- wave reduce (only when something changed in this wave) ----
            unsigned mvb = __float_as_uint(cmax);
            mvb = dpp_max_u32<0x111>(mvb);  // row_shr:1
            mvb = dpp_max_u32<0x112>(mvb);  // row_shr:2
            mvb = dpp_max_u32<0x114>(mvb);  // row_shr:4
            mvb = dpp_max_u32<0x118>(mvb);  // row_shr:8
            mvb = dpp_max_u32<0x142>(mvb);  // row_bcast15
            mvb = dpp_max_u32<0x143>(mvb);  // row_bcast31 -> lane 63 has wave max
            const unsigned wmax = (unsigned)__builtin_amdgcn_readlane((int)mvb, 63);
            unsigned midx = (__float_as_uint(cmax) == wmax) ? (unsigned)cidx : 0x7FFFFFFFu;
            midx = dpp_min_u32<0x111>(midx);
            midx = dpp_min_u32<0x112>(midx);
            midx = dpp_min_u32<0x114>(midx);
            midx = dpp_min_u32<0x118>(midx);
            midx = dpp_min_u32<0x142>(midx);
            midx = dpp_min_u32<0x143>(midx);  // lane 63 has wave arg-min index
            // pack (value, ~idx): u64 max => largest value, ties -> smallest index
            wkey = ((unsigned long long)wmax << 32) | (unsigned)(~midx);
        }
        if (lane == 63) red2[t & 1][wv] = wkey;
        __syncthreads();
        // ---- cross-wave: depth-3 tree over the 8 wave keys ----
        const unsigned long long* r = red2[t & 1];
        unsigned long long k0 = r[0], k1 = r[1], k2 = r[2], k3 = r[3];
        unsigned long long k4 = r[4], k5 = r[5], k6 = r[6], k7 = r[7];
        unsigned long long a0 = k0 > k1 ? k0 : k1;
        unsigned long long a1 = k2 > k3 ? k2 : k3;
        unsigned long long a2 = k4 > k5 ? k4 : k5;
        unsigned long long a3 = k6 > k7 ? k6 : k7;
        unsigned long long b0 = a0 > a1 ? a0 : a1;
        unsigned long long b1 = a2 > a3 ? a2 : a3;
        unsigned long long best = b0 > b1 ? b0 : b1;
        far = (int)(~(unsigned)best);
    }
    __syncthreads();
    // coalesced dump of the selected indices
    for (int t = tid; t < MM; t += 512) fps_store[t] = sfps[t];
}

// ---------------- transform: g[b][n][o] = sum_c W[o][c] * f[b][c][n] ----------------
__global__ __launch_bounds__(256) void transform_kernel(const float* __restrict__ feature,
                                                        const float* __restrict__ weight,
                                                        float* __restrict__ g) {
    __shared__ float Wl[64 * 64];
    const int tid = threadIdx.x;
    for (int k = tid; k < 64 * 64; k += 256) Wl[k] = weight[k];
    __syncthreads();

    const int P = blockIdx.x * 256 + tid;  // global point slot
    const int b = P >> 13;                 // / 8192
    const int n = P & (NN - 1);
    const float* fb = feature + (size_t)b * CC * NN + n;

    float fr[64];
#pragma unroll
    for (int c = 0; c < 64; ++c) fr[c] = fb[(size_t)c * NN];

    float* go = g + ((size_t)b << 19) + (size_t)n * 64;
    for (int o = 0; o < 64; o += 4) {
        const float* w0 = &Wl[o * 64];
        const float* w1 = w0 + 64;
        const float* w2 = w0 + 128;
        const float* w3 = w0 + 192;
        float a0 = 0.f, a1 = 0.f, a2 = 0.f, a3 = 0.f;
#pragma unroll
        for (int c = 0; c < 64; c += 4) {
            float4 v0 = *(const float4*)(w0 + c);
            float4 v1 = *(const float4*)(w1 + c);
            float4 v2 = *(const float4*)(w2 + c);
            float4 v3 = *(const float4*)(w3 + c);
            a0 += v0.x * fr[c] + v0.y * fr[c + 1] + v0.z * fr[c + 2] + v0.w * fr[c + 3];
            a1 += v1.x * fr[c] + v1.y * fr[c + 1] + v1.z * fr[c + 2] + v1.w * fr[c + 3];
            a2 += v2.x * fr[c] + v2.y * fr[c + 1] + v2.z * fr[c + 2] + v2.w * fr[c + 3];
            a3 += v3.x * fr[c] + v3.y * fr[c + 1] + v3.z * fr[c + 2] + v3.w * fr[c + 3];
        }
        float4 r;
        r.x = a0; r.y = a1; r.z = a2; r.w = a3;
        *(float4*)(go + o) = r;
    }
}

// ---------------- ball query: one wave per query; also emits x_out (coord max) ----------------
__global__ __launch_bounds__(256) void bq_kernel(const float* __restrict__ x,
                                                 const int* __restrict__ fps_idx,
                                                 int* __restrict__ sub_idx,
                                                 float* __restrict__ xout) {
    const float R2 = (float)(0.4 * 0.4);  // match python double product -> f32 cast
    int gw = (int)((blockIdx.x * 256 + threadIdx.x) >> 6);
    const int lane = threadIdx.x & 63;
    gw = __builtin_amdgcn_readfirstlane(gw);
    const int b = gw >> 11;
    const int m = gw & (MM - 1);
    const float* xb = x + (size_t)b * 3 * NN;

    const int ctr = fps_idx[gw];
    const float cx = xb[ctr];
    const float cy = xb[NN + ctr];
    const float cz = xb[2 * NN + ctr];

    int* sid = sub_idx + (size_t)gw * KK;
    int found = 0;
    int first = 0;
    float mx = -INFINITY, my = -INFINITY, mz = -INFINITY;

    for (int base = 0; base < NN; base += 64) {
        const int i = base + lane;
        const float xx = xb[i];
        const float yy = xb[NN + i];
        const float zz = xb[2 * NN + i];
        const float d2 = sqdist_exact(xx, yy, zz, cx, cy, cz);
        const bool q = d2 < R2;
        const unsigned long long mask = __ballot(q);
        if (q) {
            int pos = found + (int)__popcll(mask & ((1ull << lane) - 1ull));
            if (pos < KK) {
                sid[pos] = i;
                mx = fmaxf(mx, xx);
                my = fmaxf(my, yy);
                mz = fmaxf(mz, zz);
            }
        }
        if (found == 0 && mask != 0ull) first = base + (int)__builtin_ctzll(mask);
        found += (int)__popcll(mask);
        if (found >= KK) break;
    }
    if (found < KK) {
        if (lane < KK - found) sid[found + lane] = first;  // pad with first found index
    }
#pragma unroll
    for (int off = 32; off >= 1; off >>= 1) {
        mx = fmaxf(mx, __shfl_xor(mx, off, 64));
        my = fmaxf(my, __shfl_xor(my, off, 64));
        mz = fmaxf(mz, __shfl_xor(mz, off, 64));
    }
    if (lane == 0) {
        xout[(size_t)b * 3 * MM + 0 * MM + m] = mx;
        xout[(size_t)b * 3 * MM + 1 * MM + m] = my;
        xout[(size_t)b * 3 * MM + 2 * MM + m] = mz;
    }
}

// ---------------- gather-max: f_out[b][o][m] = max_j g[b][idx_j][o] ----------------
__global__ __launch_bounds__(256) void gather_kernel(const float* __restrict__ g,
                                                     const int* __restrict__ sub_idx,
                                                     float* __restrict__ fout) {
    int gw = (int)((blockIdx.x * 256 + threadIdx.x) >> 6);
    const int lane = threadIdx.x & 63;
    gw = __builtin_amdgcn_readfirstlane(gw);
    const int b = gw >> 11;
    const int m = gw & (MM - 1);
    const int* sid = sub_idx + (size_t)gw * KK;
    const float* gb = g + ((size_t)b << 19);
    float acc = -INFINITY;
#pragma unroll
    for (int j = 0; j < KK; ++j) {
        const int id = sid[j];
        acc = fmaxf(acc, gb[(size_t)id * 64 + lane]);
    }
    fout[((size_t)b << 17) + ((size_t)lane << 11) + m] = acc;
}

extern "C" void kernel_launch(void* const* d_in, const int* in_sizes, int n_in,
                              void* d_out, int out_size, void* d_ws, size_t ws_size,
                              hipStream_t stream) {
    const float* x = (const float*)d_in[0];        // (8,3,8192)
    const float* feature = (const float*)d_in[1];  // (8,64,8192)
    const float* weight = (const float*)d_in[2];   // (64,64)
    // d_in[3] = num_pool (=2048), hard-coded as MM

    float* out = (float*)d_out;
    float* xout = out;                  // (8,3,2048)
    float* fout = out + BB * 3 * MM;    // (8,64,2048)

    char* ws = (char*)d_ws;
    int* fps_idx = (int*)ws;                                       // 64 KB
    int* sub_idx = (int*)(ws + (size_t)BB * MM * 4);               // 2 MB
    float* g = (float*)(ws + (size_t)BB * MM * 4 + (size_t)BB * MM * KK * 4);  // 16 MB

    fps_kernel<<<BB, 512, 0, stream>>>(x, fps_idx);
    transform_kernel<<<(BB * NN) / 256, 256, 0, stream>>>(feature, weight, g);
    bq_kernel<<<(BB * MM * 64) / 256, 256, 0, stream>>>(x, fps_idx, sub_idx, xout);
    gather_kernel<<<(BB * MM * 64) / 256, 256, 0, stream>>>(g, sub_idx, fout);
}

// Round 5
// 1922.956 us; speedup vs baseline: 1.1829x; 1.1829x over previous
//
#include <hip/hip_runtime.h>
#include <cstdint>
#include <cstddef>

#define BB 8
#define NN 8192
#define CC 64
#define MM 2048
#define KK 32

typedef float vfloat2 __attribute__((ext_vector_type(2)));

__device__ __forceinline__ float sqdist_exact(float x, float y, float z,
                                              float cx, float cy, float cz) {
    // Replicate numpy/JAX f32: (x-c)**2 summed ((dx2+dy2)+dz2), no FMA contraction.
    float dx = __fsub_rn(x, cx);
    float dy = __fsub_rn(y, cy);
    float dz = __fsub_rn(z, cz);
    return __fadd_rn(__fadd_rn(__fmul_rn(dx, dx), __fmul_rn(dy, dy)),
                     __fmul_rn(dz, dz));
}

// ---- DPP wave64 reduce ladder pieces (row_shr:N = 0x110|N, bcast15/31 = 0x142/0x143) ----
// max over nonneg f32 reinterpreted as u32 (identical ordering); bound_ctrl=true -> 0 never wins max.
template <int CTRL>
__device__ __forceinline__ unsigned dpp_max_u32(unsigned v) {
    unsigned s = (unsigned)__builtin_amdgcn_update_dpp(0, (int)v, CTRL, 0xF, 0xF, true);
    return v > s ? v : s;
}
// min over u32 indices; bound_ctrl=false with old=INT_MAX -> invalid lanes never win min.
template <int CTRL>
__device__ __forceinline__ unsigned dpp_min_u32(unsigned v) {
    unsigned s = (unsigned)__builtin_amdgcn_update_dpp(0x7FFFFFFF, (int)v, CTRL, 0xF, 0xF, false);
    return v < s ? v : s;
}

// Octile boundaries of N(0,1): equal-mass 8-way split per dimension.
__device__ __forceinline__ int octile(float v) {
    return (v > -1.1503494f) + (v > -0.6744898f) + (v > -0.3186394f) + (v > 0.0f) +
           (v > 0.3186394f) + (v > 0.6744898f) + (v > 1.1503494f);
}

// 9-bit Morton interleave of three 3-bit coords: consecutive bin ids are
// spatially compact (each wave's 64 bins form a 4x4x4 sub-cube).
__device__ __forceinline__ int morton9(int bx, int by, int bz) {
    int m = (bz & 1) | ((bz & 2) << 2) | ((bz & 4) << 4);
    m |= ((by & 1) << 1) | ((by & 2) << 3) | ((by & 4) << 5);
    m |= ((bx & 1) << 2) | ((bx & 2) << 4) | ((bx & 4) << 6);
    return m;
}

// ---------------- FPS: one block per batch, 512 threads ----------------
// r5 = r3's verified control flow (per-lane predicated update via execz,
// UNCONDITIONAL split u32 DPP ladders, LDS sfps, no global ops in loop)
// + packed vfloat2 update body (halves predicated-body issue)
// + cross-wave reduce via one LDS ds_max_u64 slot (triple-buffered) instead
//   of 8-key read + depth-3 tree (shortens the post-barrier serial tail).
__global__ __launch_bounds__(512) void fps_kernel(const float* __restrict__ x,
                                                  int* __restrict__ fps_idx) {
#pragma clang fp contract(off)
    const int b = blockIdx.x;
    const int tid = threadIdx.x;
    const int lane = tid & 63;
    const float* xb = x + (size_t)b * 3 * NN;
    int* fps_store = fps_idx + b * MM;

    __shared__ float sx[NN];   // original-index order (centroid lookup)
    __shared__ float sy[NN];
    __shared__ float sz[NN];
    __shared__ int sidx[NN];   // binned order -> original index
    __shared__ int hist[512];
    __shared__ int scanb[512];
    __shared__ int sfps[MM];   // selected indices, dumped to global at the end
    __shared__ unsigned long long red3[3];  // triple-buffered atomic-max slot

    const vfloat2* gx = (const vfloat2*)xb;
    const vfloat2* gy = (const vfloat2*)(xb + NN);
    const vfloat2* gz = (const vfloat2*)(xb + 2 * NN);

    vfloat2 lx[8], ly[8], lz[8];
#pragma unroll
    for (int p = 0; p < 8; ++p) {
        const int e = tid + p * 512;  // float2 slot; covers points 2e, 2e+1
        lx[p] = gx[e];
        ly[p] = gy[e];
        lz[p] = gz[e];
        ((vfloat2*)sx)[e] = lx[p];
        ((vfloat2*)sy)[e] = ly[p];
        ((vfloat2*)sz)[e] = lz[p];
    }
    hist[tid] = 0;
    if (tid < 3) red3[tid] = 0ull;
    __syncthreads();

    // ---- histogram over 512 morton-octile bins (from registers) ----
    int mybin[16];
#pragma unroll
    for (int p = 0; p < 8; ++p) {
        int b0 = morton9(octile(lx[p].x), octile(ly[p].x), octile(lz[p].x));
        int b1 = morton9(octile(lx[p].y), octile(ly[p].y), octile(lz[p].y));
        mybin[2 * p] = b0;
        mybin[2 * p + 1] = b1;
        atomicAdd(&hist[b0], 1);
        atomicAdd(&hist[b1], 1);
    }
    __syncthreads();
    // ---- exclusive prefix sum (Hillis-Steele, 512 threads == 512 bins) ----
    int own = hist[tid];
    scanb[tid] = own;
    __syncthreads();
    for (int off = 1; off < 512; off <<= 1) {
        int add = (tid >= off) ? scanb[tid - off] : 0;
        __syncthreads();
        scanb[tid] += add;
        __syncthreads();
    }
    hist[tid] = scanb[tid] - own;  // per-bin scatter cursor
    __syncthreads();
    // ---- scatter original indices into binned order ----
#pragma unroll
    for (int p = 0; p < 8; ++p) {
        const int i0 = 2 * (tid + p * 512);
        int pos0 = atomicAdd(&hist[mybin[2 * p]], 1);
        sidx[pos0] = i0;
        int pos1 = atomicAdd(&hist[mybin[2 * p + 1]], 1);
        sidx[pos1] = i0 + 1;
    }
    __syncthreads();

    // ---- gather this thread's 16-point chunk (packed pairs) + bbox ----
    vfloat2 px[8], py[8], pz[8], dist[8];
    int idxr[16];
#pragma unroll
    for (int p = 0; p < 8; ++p) {
        const int j0 = sidx[tid * 16 + 2 * p];
        const int j1 = sidx[tid * 16 + 2 * p + 1];
        idxr[2 * p] = j0;
        idxr[2 * p + 1] = j1;
        px[p] = (vfloat2){sx[j0], sx[j1]};
        py[p] = (vfloat2){sy[j0], sy[j1]};
        pz[p] = (vfloat2){sz[j0], sz[j1]};
        dist[p] = (vfloat2){INFINITY, INFINITY};
    }
    float blx = fminf(px[0].x, px[0].y), bhx = fmaxf(px[0].x, px[0].y);
    float bly = fminf(py[0].x, py[0].y), bhy = fmaxf(py[0].x, py[0].y);
    float blz = fminf(pz[0].x, pz[0].y), bhz = fmaxf(pz[0].x, pz[0].y);
#pragma unroll
    for (int p = 1; p < 8; ++p) {
        blx = fminf(blx, fminf(px[p].x, px[p].y));
        bhx = fmaxf(bhx, fmaxf(px[p].x, px[p].y));
        bly = fminf(bly, fminf(py[p].x, py[p].y));
        bhy = fmaxf(bhy, fmaxf(py[p].x, py[p].y));
        blz = fminf(blz, fminf(pz[p].x, pz[p].y));
        bhz = fmaxf(bhz, fmaxf(pz[p].x, pz[p].y));
    }

    float cmax = INFINITY;  // exact max of this chunk's current dists
    int cidx = idxr[0];     // smallest original index achieving cmax
    int far = 0;
    for (int t = 0; t < MM; ++t) {
        if (tid == 0) {
            sfps[t] = far;                 // LDS only: no vmcnt drain at barrier
            red3[(t + 1) % 3] = 0ull;      // pre-reset next slot (readers of its
        }                                  // previous value all passed barrier t-1)
        const float cx = sx[far];
        const float cy = sy[far];
        const float cz = sz[far];

        // Lower bound on d^2(c, bbox) via clamp (v_med3). 0.999f margin >>
        // f32 rounding slack (~1.5e-6 rel) between this bound and the exact
        // per-point pipeline, so skipping is guaranteed a value-exact no-op.
        float qx = cx - fminf(fmaxf(cx, blx), bhx);
        float qy = cy - fminf(fmaxf(cy, bly), bhy);
        float qz = cz - fminf(fmaxf(cz, blz), bhz);
        float bound = (qx * qx + qy * qy) + qz * qz;
        const bool act = !(bound * 0.999f >= cmax);
        if (act) {  // per-lane predication; compiler wave-skips via execz
            const vfloat2 cx2 = {cx, cx};
            const vfloat2 cy2 = {cy, cy};
            const vfloat2 cz2 = {cz, cz};
            float mv = -1.0f;
#pragma unroll
            for (int p = 0; p < 8; ++p) {
                vfloat2 dx = px[p] - cx2;   // v_pk_add_f32
                vfloat2 dy = py[p] - cy2;
                vfloat2 dz = pz[p] - cz2;
                vfloat2 m1 = dx * dx;       // v_pk_mul_f32
                vfloat2 m2 = dy * dy;
                vfloat2 m3 = dz * dz;
                vfloat2 s = (m1 + m2) + m3; // matches reference order
                vfloat2 nd;
                nd.x = fminf(dist[p].x, s.x);
                nd.y = fminf(dist[p].y, s.y);
                dist[p] = nd;
                mv = fmaxf(fmaxf(mv, nd.x), nd.y);  // -> v_max3_f32
            }
            // smallest ORIGINAL index among chunk maxima (binned != idx order)
            int mi = 0x7FFFFFFF;
#pragma unroll
            for (int p = 0; p < 8; ++p) {
                mi = min(mi, (dist[p].x == mv) ? idxr[2 * p] : 0x7FFFFFFF);
                mi = min(mi, (dist[p].y == mv) ? idxr[2 * p + 1] : 0x7FFFFFFF);
            }
            cmax = mv;
            cidx = mi;
        }

        // ---- wave reduce (unconditional, all waves — r3-proven): u32 max of
        //      dist bits (== f32 order, nonneg), then u32 min of tie-masked idx ----
        unsigned mvb = __float_as_uint(cmax);
        mvb = dpp_max_u32<0x111>(mvb);  // row_shr:1
        mvb = dpp_max_u32<0x112>(mvb);  // row_shr:2
        mvb = dpp_max_u32<0x114>(mvb);  // row_shr:4
        mvb = dpp_max_u32<0x118>(mvb);  // row_shr:8
        mvb = dpp_max_u32<0x142>(mvb);  // row_bcast15
        mvb = dpp_max_u32<0x143>(mvb);  // row_bcast31 -> lane 63 has wave max
        const unsigned wmax = (unsigned)__builtin_amdgcn_readlane((int)mvb, 63);
        unsigned midx = (__float_as_uint(cmax) == wmax) ? (unsigned)cidx : 0x7FFFFFFFu;
        midx = dpp_min_u32<0x111>(midx);
        midx = dpp_min_u32<0x112>(midx);
        midx = dpp_min_u32<0x114>(midx);
        midx = dpp_min_u32<0x118>(midx);
        midx = dpp_min_u32<0x142>(midx);
        midx = dpp_min_u32<0x143>(midx);  // lane 63 has wave arg-min index
        if (lane == 63) {
            // pack (value, ~idx): u64 max => largest value, ties -> smallest idx.
            // key is always > 0 (~midx >= 0xFFFFE000), so the 0-reset never wins.
            unsigned long long key =
                ((unsigned long long)wmax << 32) | (unsigned)(~midx);
            atomicMax(&red3[t % 3], key);  // ds_max_u64, 8 writers
        }
        __syncthreads();
        far = (int)(~(unsigned)red3[t % 3]);  // one 8B LDS broadcast read
    }
    __syncthreads();
    // coalesced dump of the selected indices
    for (int t = tid; t < MM; t += 512) fps_store[t] = sfps[t];
}

// ---------------- transform: g[b][n][o] = sum_c W[o][c] * f[b][c][n] ----------------
__global__ __launch_bounds__(256) void transform_kernel(const float* __restrict__ feature,
                                                        const float* __restrict__ weight,
                                                        float* __restrict__ g) {
    __shared__ float Wl[64 * 64];
    const int tid = threadIdx.x;
    for (int k = tid; k < 64 * 64; k += 256) Wl[k] = weight[k];
    __syncthreads();

    const int P = blockIdx.x * 256 + tid;  // global point slot
    const int b = P >> 13;                 // / 8192
    const int n = P & (NN - 1);
    const float* fb = feature + (size_t)b * CC * NN + n;

    float fr[64];
#pragma unroll
    for (int c = 0; c < 64; ++c) fr[c] = fb[(size_t)c * NN];

    float* go = g + ((size_t)b << 19) + (size_t)n * 64;
    for (int o = 0; o < 64; o += 4) {
        const float* w0 = &Wl[o * 64];
        const float* w1 = w0 + 64;
        const float* w2 = w0 + 128;
        const float* w3 = w0 + 192;
        float a0 = 0.f, a1 = 0.f, a2 = 0.f, a3 = 0.f;
#pragma unroll
        for (int c = 0; c < 64; c += 4) {
            float4 v0 = *(const float4*)(w0 + c);
            float4 v1 = *(const float4*)(w1 + c);
            float4 v2 = *(const float4*)(w2 + c);
            float4 v3 = *(const float4*)(w3 + c);
            a0 += v0.x * fr[c] + v0.y * fr[c + 1] + v0.z * fr[c + 2] + v0.w * fr[c + 3];
            a1 += v1.x * fr[c] + v1.y * fr[c + 1] + v1.z * fr[c + 2] + v1.w * fr[c + 3];
            a2 += v2.x * fr[c] + v2.y * fr[c + 1] + v2.z * fr[c + 2] + v2.w * fr[c + 3];
            a3 += v3.x * fr[c] + v3.y * fr[c + 1] + v3.z * fr[c + 2] + v3.w * fr[c + 3];
        }
        float4 r;
        r.x = a0; r.y = a1; r.z = a2; r.w = a3;
        *(float4*)(go + o) = r;
    }
}

// ---------------- ball query: one wave per query; also emits x_out (coord max) ----------------
__global__ __launch_bounds__(256) void bq_kernel(const float* __restrict__ x,
                                                 const int* __restrict__ fps_idx,
                                                 int* __restrict__ sub_idx,
                                                 float* __restrict__ xout) {
    const float R2 = (float)(0.4 * 0.4);  // match python double product -> f32 cast
    int gw = (int)((blockIdx.x * 256 + threadIdx.x) >> 6);
    const int lane = threadIdx.x & 63;
    gw = __builtin_amdgcn_readfirstlane(gw);
    const int b = gw >> 11;
    const int m = gw & (MM - 1);
    const float* xb = x + (size_t)b * 3 * NN;

    const int ctr = fps_idx[gw];
    const float cx = xb[ctr];
    const float cy = xb[NN + ctr];
    const float cz = xb[2 * NN + ctr];

    int* sid = sub_idx + (size_t)gw * KK;
    int found = 0;
    int first = 0;
    float mx = -INFINITY, my = -INFINITY, mz = -INFINITY;

    for (int base = 0; base < NN; base += 64) {
        const int i = base + lane;
        const float xx = xb[i];
        const float yy = xb[NN + i];
        const float zz = xb[2 * NN + i];
        const float d2 = sqdist_exact(xx, yy, zz, cx, cy, cz);
        const bool q = d2 < R2;
        const unsigned long long mask = __ballot(q);
        if (q) {
            int pos = found + (int)__popcll(mask & ((1ull << lane) - 1ull));
            if (pos < KK) {
                sid[pos] = i;
                mx = fmaxf(mx, xx);
                my = fmaxf(my, yy);
                mz = fmaxf(mz, zz);
            }
        }
        if (found == 0 && mask != 0ull) first = base + (int)__builtin_ctzll(mask);
        found += (int)__popcll(mask);
        if (found >= KK) break;
    }
    if (found < KK) {
        if (lane < KK - found) sid[found + lane] = first;  // pad with first found index
    }
#pragma unroll
    for (int off = 32; off >= 1; off >>= 1) {
        mx = fmaxf(mx, __shfl_xor(mx, off, 64));
        my = fmaxf(my, __shfl_xor(my, off, 64));
        mz = fmaxf(mz, __shfl_xor(mz, off, 64));
    }
    if (lane == 0) {
        xout[(size_t)b * 3 * MM + 0 * MM + m] = mx;
        xout[(size_t)b * 3 * MM + 1 * MM + m] = my;
        xout[(size_t)b * 3 * MM + 2 * MM + m] = mz;
    }
}

// ---------------- gather-max: f_out[b][o][m] = max_j g[b][idx_j][o] ----------------
__global__ __launch_bounds__(256) void gather_kernel(const float* __restrict__ g,
                                                     const int* __restrict__ sub_idx,
                                                     float* __restrict__ fout) {
    int gw = (int)((blockIdx.x * 256 + threadIdx.x) >> 6);
    const int lane = threadIdx.x & 63;
    gw = __builtin_amdgcn_readfirstlane(gw);
    const int b = gw >> 11;
    const int m = gw & (MM - 1);
    const int* sid = sub_idx + (size_t)gw * KK;
    const float* gb = g + ((size_t)b << 19);
    float acc = -INFINITY;
#pragma unroll
    for (int j = 0; j < KK; ++j) {
        const int id = sid[j];
        acc = fmaxf(acc, gb[(size_t)id * 64 + lane]);
    }
    fout[((size_t)b << 17) + ((size_t)lane << 11) + m] = acc;
}

extern "C" void kernel_launch(void* const* d_in, const int* in_sizes, int n_in,
                              void* d_out, int out_size, void* d_ws, size_t ws_size,
                              hipStream_t stream) {
    const float* x = (const float*)d_in[0];        // (8,3,8192)
    const float* feature = (const float*)d_in[1];  // (8,64,8192)
    const float* weight = (const float*)d_in[2];   // (64,64)
    // d_in[3] = num_pool (=2048), hard-coded as MM

    float* out = (float*)d_out;
    float* xout = out;                  // (8,3,2048)
    float* fout = out + BB * 3 * MM;    // (8,64,2048)

    char* ws = (char*)d_ws;
    int* fps_idx = (int*)ws;                                       // 64 KB
    int* sub_idx = (int*)(ws + (size_t)BB * MM * 4);               // 2 MB
    float* g = (float*)(ws + (size_t)BB * MM * 4 + (size_t)BB * MM * KK * 4);  // 16 MB

    fps_kernel<<<BB, 512, 0, stream>>>(x, fps_idx);
    transform_kernel<<<(BB * NN) / 256, 256, 0, stream>>>(feature, weight, g);
    bq_kernel<<<(BB * MM * 64) / 256, 256, 0, stream>>>(x, fps_idx, sub_idx, xout);
    gather_kernel<<<(BB * MM * 64) / 256, 256, 0, stream>>>(g, sub_idx, fout);
}